// Round 19
// baseline (269.667 us; speedup 1.0000x reference)
//
#include <hip/hip_runtime.h>
#include <cfloat>
#include <math.h>

#define B_   8
#define V_   4096
#define E_   256
#define K_   6
#define H_   8
#define HD_  32
#define NPTS (B_*V_)

typedef __bf16 bf16x8 __attribute__((ext_vector_type(8)));
typedef float  f32x4  __attribute__((ext_vector_type(4)));
typedef float  f32x16 __attribute__((ext_vector_type(16)));

__device__ __forceinline__ float bf2f(unsigned short u) {
    return __uint_as_float(((unsigned int)u) << 16);
}
__device__ __forceinline__ unsigned short f2bf(float f) {
    unsigned int u = __float_as_uint(f);
    return (unsigned short)((u + 0x7fffu + ((u >> 16) & 1u)) >> 16);
}
__device__ __forceinline__ unsigned int med3u(unsigned int a, unsigned int b,
                                              unsigned int c) {
    unsigned int d;
    asm("v_med3_u32 %0, %1, %2, %3" : "=v"(d) : "v"(a), "v"(b), "v"(c));
    return d;
}
// branchless sorted-top-6 insert (single definition -> no transcription bugs)
__device__ __forceinline__ void push6(unsigned int (&k6)[6], unsigned int key) {
    k6[5] = med3u(k6[4], k6[5], key);
    k6[4] = med3u(k6[3], k6[4], key);
    k6[3] = med3u(k6[2], k6[3], key);
    k6[2] = med3u(k6[1], k6[2], key);
    k6[1] = med3u(k6[0], k6[1], key);
    k6[0] = min(k6[0], key);
}
// bf16 bitwise *(-1024): exponent+10, sign flip (exact; no denorm/overflow for our data)
__device__ __forceinline__ unsigned int bfscale2(unsigned int u) {
    return (u + 0x05000500u) ^ 0x80008000u;
}

// ------ k0: fp32->bf16 of x + W matrices; sq -> permuted (sq+600)*512; xw zeroing ------
__global__ __launch_bounds__(256) void cvtsq_kernel(const float* __restrict__ x,
                                                    const float* __restrict__ Wq,
                                                    const float* __restrict__ Wk,
                                                    const float* __restrict__ Wv,
                                                    const float* __restrict__ Wo,
                                                    unsigned short* __restrict__ xh,
                                                    unsigned short* __restrict__ Wh,
                                                    float* __restrict__ sqp,
                                                    float* __restrict__ xw) {
    const int bx = blockIdx.x;
    if (bx < 4096) {
        size_t i = ((size_t)bx * 256 + threadIdx.x) * 8;
        float4 a = *reinterpret_cast<const float4*>(x + i);
        float4 b = *reinterpret_cast<const float4*>(x + i + 4);
        ushort o[8] = { f2bf(a.x), f2bf(a.y), f2bf(a.z), f2bf(a.w),
                        f2bf(b.x), f2bf(b.y), f2bf(b.z), f2bf(b.w) };
        *reinterpret_cast<uint4*>(xh + i) = *reinterpret_cast<uint4*>(o);
        float s = a.x*a.x + a.y*a.y + a.z*a.z + a.w*a.w
                + b.x*b.x + b.y*b.y + b.z*b.z + b.w*b.w;
        s += __shfl_xor(s, 1);
        s += __shfl_xor(s, 2);
        s += __shfl_xor(s, 4);
        s += __shfl_xor(s, 8);
        s += __shfl_xor(s, 16);
        if ((threadIdx.x & 31) == 0) {
            int p = bx * 8 + (threadIdx.x >> 5);
            int b_ = p >> 12, col = p & 4095;
            int stripe = col >> 10, cc = col & 1023;
            int t = cc >> 5, rem = cc & 31;
            int h = (rem >> 2) & 1;
            int reg = (rem & 3) | ((rem >> 3) << 2);
            int i2 = (b_ << 12) | (stripe << 10) | (t << 5) | (h << 4) | reg;
            sqp[i2] = (s + 600.f) * 512.f;
        }
    } else {
        const int wb = bx - 4096;               // 0..127
        xw[wb * 256 + threadIdx.x] = 0.f;       // 128x256 = 32768 -> full xw zeroing
        const int m = wb >> 5;
        const float* src = (m == 0) ? Wq : (m == 1) ? Wk : (m == 2) ? Wv : Wo;
        unsigned short* dst = Wh + (size_t)m * 65536;
        size_t i = ((size_t)(wb & 31) * 256 + threadIdx.x) * 8;
        float4 a = *reinterpret_cast<const float4*>(src + i);
        float4 b = *reinterpret_cast<const float4*>(src + i + 4);
        ushort o[8] = { f2bf(a.x), f2bf(a.y), f2bf(a.z), f2bf(a.w),
                        f2bf(b.x), f2bf(b.y), f2bf(b.z), f2bf(b.w) };
        *reinterpret_cast<uint4*>(dst + i) = *reinterpret_cast<uint4*>(o);
    }
}

// ---- k1: 32x32x16 MFMA Gram, 64 rows/wave (dual B-set), 4 stripes of 1024 ----
__global__ __launch_bounds__(256, 2) void knn13_kernel(const unsigned short* __restrict__ xh,
                                                       const float* __restrict__ sqp,
                                                       unsigned int* __restrict__ cand) {
    __shared__ __align__(16) char smem[36864];   // 2x16KB tiles + 4KB sqp stripe

    const int b      = blockIdx.z;
    const int row0   = blockIdx.x * 256;
    const int stripe = blockIdx.y;
    const int colbase = stripe * 1024;
    const int tid = threadIdx.x;
    const int w   = tid >> 6;
    const int l   = tid & 63;
    const int ln  = l & 31;
    const int h   = l >> 5;
    const unsigned short* Xb = xh + ((size_t)b << 12) * E_;

    const int myrow0 = row0 + (w << 6) + ln;
    bf16x8 brow0[16], brow1[16];
#pragma unroll
    for (int kg = 0; kg < 16; ++kg) {
        uint4 u0 = *reinterpret_cast<const uint4*>(
            Xb + ((size_t)myrow0 << 8) + kg * 16 + h * 8);
        uint4 u1 = *reinterpret_cast<const uint4*>(
            Xb + ((size_t)(myrow0 + 32) << 8) + kg * 16 + h * 8);
        u0.x = bfscale2(u0.x); u0.y = bfscale2(u0.y);
        u0.z = bfscale2(u0.z); u0.w = bfscale2(u0.w);
        u1.x = bfscale2(u1.x); u1.y = bfscale2(u1.y);
        u1.z = bfscale2(u1.z); u1.w = bfscale2(u1.w);
        brow0[kg] = *reinterpret_cast<bf16x8*>(&u0);
        brow1[kg] = *reinterpret_cast<bf16x8*>(&u1);
    }

    unsigned int bk0[6], bk1[6];
#pragma unroll
    for (int s = 0; s < 6; ++s) { bk0[s] = 0xFFFFFFFFu; bk1[s] = 0xFFFFFFFFu; }

    __builtin_amdgcn_global_load_lds(
        (const __attribute__((address_space(1))) void*)
            (sqp + ((size_t)(b * 4 + stripe) << 10) + tid * 4),
        (__attribute__((address_space(3))) void*)(smem + 32768 + tid * 16), 16, 0, 0);
#pragma unroll
    for (int it = 0; it < 4; ++it) {
        int li = it * 256 + tid, col = li >> 5, sl = li & 31;
        const unsigned short* gp =
            Xb + ((size_t)(colbase + col) << 8) + ((sl ^ (col & 7)) << 3);
        __builtin_amdgcn_global_load_lds(
            (const __attribute__((address_space(1))) void*)gp,
            (__attribute__((address_space(3))) void*)(smem + li * 16), 16, 0, 0);
    }
    __syncthreads();

    for (int t = 0; t < 32; ++t) {
        const int cur = (t & 1) * 16384;
        if (t < 31) {
            char* nbuf = smem + (cur ^ 16384);
            const int c0n = colbase + (t + 1) * 32;
#pragma unroll
            for (int it = 0; it < 4; ++it) {
                int li = it * 256 + tid, col = li >> 5, sl = li & 31;
                const unsigned short* gp =
                    Xb + ((size_t)(c0n + col) << 8) + ((sl ^ (col & 7)) << 3);
                __builtin_amdgcn_global_load_lds(
                    (const __attribute__((address_space(1))) void*)gp,
                    (__attribute__((address_space(3))) void*)(nbuf + li * 16), 16, 0, 0);
            }
        }
        const char* sb = smem + 32768 + t * 128 + h * 64;
        f32x16 acc0;
#pragma unroll
        for (int q = 0; q < 4; ++q) {
            f32x4 sv = *reinterpret_cast<const f32x4*>(sb + q * 16);
            acc0[q * 4 + 0] = sv[0];
            acc0[q * 4 + 1] = sv[1];
            acc0[q * 4 + 2] = sv[2];
            acc0[q * 4 + 3] = sv[3];
        }
        f32x16 acc1 = acc0;

        const char* abase = smem + cur + ln * 512;
        const int swz = (ln & 7);
#pragma unroll
        for (int kg = 0; kg < 16; ++kg) {
            bf16x8 af = *reinterpret_cast<const bf16x8*>(
                abase + ((((kg << 1) + h) ^ swz) << 4));
            acc0 = __builtin_amdgcn_mfma_f32_32x32x16_bf16(af, brow0[kg], acc0, 0, 0, 0);
            acc1 = __builtin_amdgcn_mfma_f32_32x32x16_bf16(af, brow1[kg], acc1, 0, 0, 0);
        }

        const unsigned int cb0 = (unsigned int)(colbase + (t << 5) + (h << 2));
#pragma unroll
        for (int r = 0; r < 16; ++r) {
            unsigned int cidx = cb0 + (r & 3) + ((r >> 2) << 3);
            push6(bk0, ((unsigned int)acc0[r] << 12) | cidx);
            push6(bk1, ((unsigned int)acc1[r] << 12) | cidx);
        }
        __syncthreads();
    }

    size_t p0 = ((size_t)b << 12) + myrow0;
    unsigned int* op0 = cand + p0 * 48 + stripe * 12 + h * 6;
    unsigned int* op1 = cand + (p0 + 32) * 48 + stripe * 12 + h * 6;
#pragma unroll
    for (int s = 0; s < 6; ++s) { op0[s] = bk0[s]; op1[s] = bk1[s]; }
}

// ---------------- k1s: key-top-16 of 48; resolve boundary or flag ----------------
__global__ __launch_bounds__(256) void sel_kernel(const unsigned int* __restrict__ cand,
                                                  unsigned short* __restrict__ c16,
                                                  int* __restrict__ idxout,
                                                  unsigned char* __restrict__ flag) {
    int p = blockIdx.x * 256 + threadIdx.x;
    const unsigned int* cp = cand + (size_t)p * 48;
    unsigned int tk[16];
#pragma unroll
    for (int s = 0; s < 16; ++s) tk[s] = 0xFFFFFFFFu;
    for (int j = 0; j < 48; ++j) {
        unsigned int key = cp[j];
#pragma unroll
        for (int s = 15; s > 0; --s) tk[s] = med3u(tk[s - 1], tk[s], key);
        tk[0] = min(tk[0], key);
    }
    unsigned short* op = c16 + (size_t)p * 16;
#pragma unroll
    for (int s = 0; s < 16; ++s) op[s] = (unsigned short)(tk[s] & 4095u);
    int* ip = idxout + (size_t)p * K_;
#pragma unroll
    for (int s = 0; s < 6; ++s) ip[s] = (int)(tk[s] & 4095u);
    float d6 = (float)(tk[5] >> 12) * 0.001953125f;
    float d7 = (float)(tk[6] >> 12) * 0.001953125f;
    flag[p] = (d7 - d6 < 0.4f) ? 1 : 0;
}

// ------- k1b: fp64 exact re-rank of 16 candidates (flagged points only) -------
__global__ __launch_bounds__(256) void refine_kernel(const float* __restrict__ x,
                                                     const unsigned short* __restrict__ c16,
                                                     const unsigned char* __restrict__ flag,
                                                     int* __restrict__ idxout) {
    int wv = threadIdx.x >> 6;
    int lane = threadIdx.x & 63;
    const int bid = blockIdx.x;
    const int nbk = ((bid & 7) << 10) | (bid >> 3);
    int p = nbk * 4 + wv;
    if (!flag[p]) return;
    int b = p >> 12;
    int vi = p & 4095;
    const float* Xb = x + ((size_t)b << 12) * E_;
    const int half = lane >> 5;
    const int hl = lane & 31;

    double xi[8];
#pragma unroll
    for (int t = 0; t < 8; ++t) xi[t] = (double)Xb[(size_t)vi * E_ + hl + t * 32];

    double bdist[6]; int bidx[6];
#pragma unroll
    for (int s = 0; s < 6; ++s) { bdist[s] = DBL_MAX; bidx[s] = 0x7fffffff; }

    const unsigned short* cp = c16 + (size_t)p * 16;
    for (int c = 0; c < 16; c += 2) {
        int jme = cp[c + half];
        const float* Xj = Xb + (size_t)jme * E_;
        double s = 0.0;
#pragma unroll
        for (int t = 0; t < 8; ++t) {
            double d = xi[t] - (double)Xj[hl + t * 32];
            s = fma(d, d, s);
        }
#pragma unroll
        for (int off = 16; off; off >>= 1) s += __shfl_xor(s, off);
        double sv[2];
        sv[0] = __shfl(s, 0);
        sv[1] = __shfl(s, 32);
        int jv[2] = { (int)cp[c], (int)cp[c + 1] };
#pragma unroll
        for (int q = 0; q < 2; ++q) {
            double sq_ = sv[q]; int j = jv[q];
            if (sq_ < bdist[5] || (sq_ == bdist[5] && j < bidx[5])) {
                bdist[5] = sq_; bidx[5] = j;
#pragma unroll
                for (int t = 5; t > 0; --t) {
                    if (bdist[t] < bdist[t - 1] ||
                        (bdist[t] == bdist[t - 1] && bidx[t] < bidx[t - 1])) {
                        double td = bdist[t]; bdist[t] = bdist[t - 1]; bdist[t - 1] = td;
                        int    ti = bidx[t];  bidx[t]  = bidx[t - 1];  bidx[t - 1]  = ti;
                    } else break;
                }
            }
        }
    }
    if (lane == 0) {
        int* op = idxout + (size_t)p * K_;
#pragma unroll
        for (int s = 0; s < 6; ++s) op[s] = bidx[s];
    }
}

// -------- k2: Q,K,V projection in ONE pass: A-fragments read once, 3 W-loops --------
__global__ __launch_bounds__(256, 2) void proj3_mfma(const unsigned short* __restrict__ xh,
                                                     const unsigned short* __restrict__ Wh,
                                                     unsigned short* __restrict__ Y) {
    const int tid = threadIdx.x;
    const int w = tid >> 6, l = tid & 63, cl = l & 15, g = l >> 4;
    const int row0 = blockIdx.x * 64;

    bf16x8 a[8];
    const int ar = row0 + (w << 4) + cl;
#pragma unroll
    for (int ks = 0; ks < 8; ++ks)
        a[ks] = *reinterpret_cast<const bf16x8*>(xh + ((size_t)ar << 8) + ks * 32 + g * 8);

#pragma unroll
    for (int wsel = 0; wsel < 3; ++wsel) {
        const unsigned short* W = Wh + (size_t)wsel * 65536;
#pragma unroll
        for (int ct = 0; ct < 16; ++ct) {
            f32x4 acc = {0.f, 0.f, 0.f, 0.f};
            const unsigned short* Wr = W + (size_t)(ct * 16 + cl) * 256 + g * 8;
#pragma unroll
            for (int ks = 0; ks < 8; ++ks) {
                bf16x8 bf = *reinterpret_cast<const bf16x8*>(Wr + ks * 32);
                acc = __builtin_amdgcn_mfma_f32_16x16x32_bf16(a[ks], bf, acc, 0, 0, 0);
            }
#pragma unroll
            for (int r = 0; r < 4; ++r) {
                size_t row = row0 + (w << 4) + (g << 2) + r;
                Y[row * 768 + wsel * 256 + ct * 16 + cl] = f2bf(acc[r]);
            }
        }
    }
}

// ---- k3: fused attention + Wo GEMM + residual. Block = 16 points ----
__global__ __launch_bounds__(256) void attn16_kernel(const unsigned short* __restrict__ Y,
                                                     const int* __restrict__ idx,
                                                     const unsigned short* __restrict__ WoH,
                                                     const float* __restrict__ x,
                                                     float* __restrict__ out,
                                                     float* __restrict__ xw) {
    __shared__ __align__(16) unsigned short P[16][264];   // +8 pad vs bank conflicts
    const int bid = blockIdx.x;                           // 2048
    const int blk = ((bid & 7) << 8) | (bid >> 3);        // XCD swizzle: XCD c -> batch c
    const int w = threadIdx.x >> 6;
    const int l = threadIdx.x & 63;
    const int p0 = blk * 16;
    const int b = p0 >> 12;
    const size_t bbase = (size_t)(b << 12) * 768;

    for (int j = 0; j < 4; ++j) {
        const int p = p0 + w * 4 + j;
        const int* ip = idx + (size_t)p * K_;
        int nb[K_];
#pragma unroll
        for (int k = 0; k < K_; ++k) nb[k] = ip[k];

        const unsigned short* Yp = Y + (size_t)p * 768;
        ushort4 q4 = *reinterpret_cast<const ushort4*>(Yp + l * 4);
        ushort4 s4 = *reinterpret_cast<const ushort4*>(Yp + 512 + l * 4);
        float q0 = bf2f(q4.x), q1 = bf2f(q4.y), q2 = bf2f(q4.z), q3 = bf2f(q4.w);
        float v0 = bf2f(s4.x), v1 = bf2f(s4.y), v2 = bf2f(s4.z), v3 = bf2f(s4.w);

        float sc[K_];
#pragma unroll
        for (int k = 0; k < K_; ++k) {
            ushort4 k4 = *reinterpret_cast<const ushort4*>(
                Y + bbase + (size_t)nb[k] * 768 + 256 + l * 4);
            float s = q0 * bf2f(k4.x) + q1 * bf2f(k4.y)
                    + q2 * bf2f(k4.z) + q3 * bf2f(k4.w);
            s += __shfl_xor(s, 1);
            s += __shfl_xor(s, 2);
            s += __shfl_xor(s, 4);
            sc[k] = s * 0.17677669529663687f;   // 1/sqrt(32)
        }
        float m = sc[0];
#pragma unroll
        for (int k = 1; k < K_; ++k) m = fmaxf(m, sc[k]);
        float e[K_], sum = 0.f;
#pragma unroll
        for (int k = 0; k < K_; ++k) { e[k] = __expf(sc[k] - m); sum += e[k]; }
        float inv = 1.f / sum;

        float o0 = 0.f, o1 = 0.f, o2 = 0.f, o3 = 0.f;
        float hs[K_];
#pragma unroll
        for (int k = 0; k < K_; ++k) {
            float a = e[k] * inv;
            ushort4 z4 = *reinterpret_cast<const ushort4*>(
                Y + bbase + (size_t)nb[k] * 768 + 512 + l * 4);
            o0 += a * (bf2f(z4.x) - v0);
            o1 += a * (bf2f(z4.y) - v1);
            o2 += a * (bf2f(z4.z) - v2);
            o3 += a * (bf2f(z4.w) - v3);
            float t = a;
            t += __shfl_xor(t, 8);
            t += __shfl_xor(t, 16);
            t += __shfl_xor(t, 32);
            hs[k] = t * 0.125f;
        }
        ushort o4[4] = { f2bf(o0), f2bf(o1), f2bf(o2), f2bf(o3) };
        *reinterpret_cast<ushort4*>(&P[w * 4 + j][l * 4]) =
            *reinterpret_cast<ushort4*>(o4);
        if (l < K_) atomicAdd(&xw[(b << 12) + nb[l]], hs[l]);
    }
    __syncthreads();

    // 16x256 P @ Wo^T + x ; wave w computes output cols [w*64, w*64+64)
    const int cl = l & 15, g = l >> 4;
    bf16x8 a[8];
#pragma unroll
    for (int ks = 0; ks < 8; ++ks)
        a[ks] = *reinterpret_cast<const bf16x8*>(&P[cl][ks * 32 + g * 8]);

#pragma unroll
    for (int ct = 0; ct < 4; ++ct) {
        const int col0 = w * 64 + ct * 16;
        f32x4 acc = {0.f, 0.f, 0.f, 0.f};
        const unsigned short* Wr = WoH + (size_t)(col0 + cl) * 256 + g * 8;
#pragma unroll
        for (int ks = 0; ks < 8; ++ks) {
            bf16x8 bf = *reinterpret_cast<const bf16x8*>(Wr + ks * 32);
            acc = __builtin_amdgcn_mfma_f32_16x16x32_bf16(a[ks], bf, acc, 0, 0, 0);
        }
#pragma unroll
        for (int r = 0; r < 4; ++r) {
            size_t o = (size_t)(p0 + (g << 2) + r) * E_ + col0 + cl;
            out[o] = acc[r] + x[o];
        }
    }
}

extern "C" void kernel_launch(void* const* d_in, const int* in_sizes, int n_in,
                              void* d_out, int out_size, void* d_ws, size_t ws_size,
                              hipStream_t stream) {
    const float* x  = (const float*)d_in[0];
    const float* Wq = (const float*)d_in[1];
    const float* Wk = (const float*)d_in[2];
    const float* Wv = (const float*)d_in[3];
    const float* Wo = (const float*)d_in[4];

    float* out = (float*)d_out;
    float* xw  = out + (size_t)NPTS * E_;   // second output [B,V]

    // workspace layout (R15-proven)
    char* ws = (char*)d_ws;
    float*          sqpw  = (float*)(ws + 131072);               // 128 KiB (permuted)
    unsigned int*   candw = (unsigned int*)(ws + 262144);        // 6 MiB (48 uint/pt)
    int*            idxw  = (int*)(ws + 6553600);                // 768 KiB
    unsigned char*  flagw = (unsigned char*)(ws + 7340032);      // 32 KiB
    unsigned short* Wh    = (unsigned short*)(ws + 7372800);     // 512 KiB (4 matrices)
    unsigned short* c16w  = (unsigned short*)(ws + 7897088);     // 1 MiB
    unsigned short* Xh    = (unsigned short*)(ws + 8945664);     // 16 MiB
    unsigned short* Y     = (unsigned short*)(ws + 25722880);    // 48 MiB bf16 [32768][768]

    cvtsq_kernel<<<4096 + 128, 256, 0, stream>>>(x, Wq, Wk, Wv, Wo, Xh, Wh, sqpw, xw);
    knn13_kernel<<<dim3(V_ / 256, 4, B_), 256, 0, stream>>>(Xh, sqpw, candw);
    sel_kernel<<<NPTS / 256, 256, 0, stream>>>(candw, c16w, idxw, flagw);
    refine_kernel<<<NPTS / 4, 256, 0, stream>>>(x, c16w, flagw, idxw);
    proj3_mfma<<<NPTS / 64, 256, 0, stream>>>(Xh, Wh, Y);
    attn16_kernel<<<NPTS / 16, 256, 0, stream>>>(Y, idxw, Wh + 3 * 65536, x, out, xw);
}

// Round 20
// 229.270 us; speedup vs baseline: 1.1762x; 1.1762x over previous
//
#include <hip/hip_runtime.h>
#include <cfloat>
#include <math.h>

#define B_   8
#define V_   4096
#define E_   256
#define K_   6
#define H_   8
#define HD_  32
#define NPTS (B_*V_)

typedef __bf16 bf16x8 __attribute__((ext_vector_type(8)));
typedef float  f32x4  __attribute__((ext_vector_type(4)));
typedef float  f32x16 __attribute__((ext_vector_type(16)));

__device__ __forceinline__ float bf2f(unsigned short u) {
    return __uint_as_float(((unsigned int)u) << 16);
}
__device__ __forceinline__ unsigned short f2bf(float f) {
    unsigned int u = __float_as_uint(f);
    return (unsigned short)((u + 0x7fffu + ((u >> 16) & 1u)) >> 16);
}
__device__ __forceinline__ unsigned int med3u(unsigned int a, unsigned int b,
                                              unsigned int c) {
    unsigned int d;
    asm("v_med3_u32 %0, %1, %2, %3" : "=v"(d) : "v"(a), "v"(b), "v"(c));
    return d;
}
// branchless sorted-top-6 insert (single definition -> no transcription bugs)
__device__ __forceinline__ void push6(unsigned int (&k6)[6], unsigned int key) {
    k6[5] = med3u(k6[4], k6[5], key);
    k6[4] = med3u(k6[3], k6[4], key);
    k6[3] = med3u(k6[2], k6[3], key);
    k6[2] = med3u(k6[1], k6[2], key);
    k6[1] = med3u(k6[0], k6[1], key);
    k6[0] = min(k6[0], key);
}
// bf16 bitwise *(-1024): exponent+10, sign flip (exact; no denorm/overflow for our data)
__device__ __forceinline__ unsigned int bfscale2(unsigned int u) {
    return (u + 0x05000500u) ^ 0x80008000u;
}

// ------ k0: fp32->bf16 of x + W matrices; sq -> permuted (sq+600)*512; xw zeroing ------
__global__ __launch_bounds__(256) void cvtsq_kernel(const float* __restrict__ x,
                                                    const float* __restrict__ Wq,
                                                    const float* __restrict__ Wk,
                                                    const float* __restrict__ Wv,
                                                    const float* __restrict__ Wo,
                                                    unsigned short* __restrict__ xh,
                                                    unsigned short* __restrict__ Wh,
                                                    float* __restrict__ sqp,
                                                    float* __restrict__ xw) {
    const int bx = blockIdx.x;
    if (bx < 4096) {
        size_t i = ((size_t)bx * 256 + threadIdx.x) * 8;
        float4 a = *reinterpret_cast<const float4*>(x + i);
        float4 b = *reinterpret_cast<const float4*>(x + i + 4);
        ushort o[8] = { f2bf(a.x), f2bf(a.y), f2bf(a.z), f2bf(a.w),
                        f2bf(b.x), f2bf(b.y), f2bf(b.z), f2bf(b.w) };
        *reinterpret_cast<uint4*>(xh + i) = *reinterpret_cast<uint4*>(o);
        float s = a.x*a.x + a.y*a.y + a.z*a.z + a.w*a.w
                + b.x*b.x + b.y*b.y + b.z*b.z + b.w*b.w;
        s += __shfl_xor(s, 1);
        s += __shfl_xor(s, 2);
        s += __shfl_xor(s, 4);
        s += __shfl_xor(s, 8);
        s += __shfl_xor(s, 16);
        if ((threadIdx.x & 31) == 0) {
            int p = bx * 8 + (threadIdx.x >> 5);
            int b_ = p >> 12, col = p & 4095;
            int stripe = col >> 10, cc = col & 1023;
            int t = cc >> 5, rem = cc & 31;
            int h = (rem >> 2) & 1;
            int reg = (rem & 3) | ((rem >> 3) << 2);
            int i2 = (b_ << 12) | (stripe << 10) | (t << 5) | (h << 4) | reg;
            sqp[i2] = (s + 600.f) * 512.f;
        }
    } else {
        const int wb = bx - 4096;               // 0..127
        xw[wb * 256 + threadIdx.x] = 0.f;       // 128x256 = 32768 -> full xw zeroing
        const int m = wb >> 5;
        const float* src = (m == 0) ? Wq : (m == 1) ? Wk : (m == 2) ? Wv : Wo;
        unsigned short* dst = Wh + (size_t)m * 65536;
        size_t i = ((size_t)(wb & 31) * 256 + threadIdx.x) * 8;
        float4 a = *reinterpret_cast<const float4*>(src + i);
        float4 b = *reinterpret_cast<const float4*>(src + i + 4);
        ushort o[8] = { f2bf(a.x), f2bf(a.y), f2bf(a.z), f2bf(a.w),
                        f2bf(b.x), f2bf(b.y), f2bf(b.z), f2bf(b.w) };
        *reinterpret_cast<uint4*>(dst + i) = *reinterpret_cast<uint4*>(o);
    }
}

// ---- k1: 32x32x16 MFMA Gram, 64 rows/wave (dual B-set), 4 stripes of 1024 ----
__global__ __launch_bounds__(256, 2) void knn13_kernel(const unsigned short* __restrict__ xh,
                                                       const float* __restrict__ sqp,
                                                       unsigned int* __restrict__ cand) {
    __shared__ __align__(16) char smem[36864];   // 2x16KB tiles + 4KB sqp stripe

    const int b      = blockIdx.z;
    const int row0   = blockIdx.x * 256;
    const int stripe = blockIdx.y;
    const int colbase = stripe * 1024;
    const int tid = threadIdx.x;
    const int w   = tid >> 6;
    const int l   = tid & 63;
    const int ln  = l & 31;
    const int h   = l >> 5;
    const unsigned short* Xb = xh + ((size_t)b << 12) * E_;

    const int myrow0 = row0 + (w << 6) + ln;
    bf16x8 brow0[16], brow1[16];
#pragma unroll
    for (int kg = 0; kg < 16; ++kg) {
        uint4 u0 = *reinterpret_cast<const uint4*>(
            Xb + ((size_t)myrow0 << 8) + kg * 16 + h * 8);
        uint4 u1 = *reinterpret_cast<const uint4*>(
            Xb + ((size_t)(myrow0 + 32) << 8) + kg * 16 + h * 8);
        u0.x = bfscale2(u0.x); u0.y = bfscale2(u0.y);
        u0.z = bfscale2(u0.z); u0.w = bfscale2(u0.w);
        u1.x = bfscale2(u1.x); u1.y = bfscale2(u1.y);
        u1.z = bfscale2(u1.z); u1.w = bfscale2(u1.w);
        brow0[kg] = *reinterpret_cast<bf16x8*>(&u0);
        brow1[kg] = *reinterpret_cast<bf16x8*>(&u1);
    }

    unsigned int bk0[6], bk1[6];
#pragma unroll
    for (int s = 0; s < 6; ++s) { bk0[s] = 0xFFFFFFFFu; bk1[s] = 0xFFFFFFFFu; }

    __builtin_amdgcn_global_load_lds(
        (const __attribute__((address_space(1))) void*)
            (sqp + ((size_t)(b * 4 + stripe) << 10) + tid * 4),
        (__attribute__((address_space(3))) void*)(smem + 32768 + tid * 16), 16, 0, 0);
#pragma unroll
    for (int it = 0; it < 4; ++it) {
        int li = it * 256 + tid, col = li >> 5, sl = li & 31;
        const unsigned short* gp =
            Xb + ((size_t)(colbase + col) << 8) + ((sl ^ (col & 7)) << 3);
        __builtin_amdgcn_global_load_lds(
            (const __attribute__((address_space(1))) void*)gp,
            (__attribute__((address_space(3))) void*)(smem + li * 16), 16, 0, 0);
    }
    __syncthreads();

    for (int t = 0; t < 32; ++t) {
        const int cur = (t & 1) * 16384;
        if (t < 31) {
            char* nbuf = smem + (cur ^ 16384);
            const int c0n = colbase + (t + 1) * 32;
#pragma unroll
            for (int it = 0; it < 4; ++it) {
                int li = it * 256 + tid, col = li >> 5, sl = li & 31;
                const unsigned short* gp =
                    Xb + ((size_t)(c0n + col) << 8) + ((sl ^ (col & 7)) << 3);
                __builtin_amdgcn_global_load_lds(
                    (const __attribute__((address_space(1))) void*)gp,
                    (__attribute__((address_space(3))) void*)(nbuf + li * 16), 16, 0, 0);
            }
        }
        const char* sb = smem + 32768 + t * 128 + h * 64;
        f32x16 acc0;
#pragma unroll
        for (int q = 0; q < 4; ++q) {
            f32x4 sv = *reinterpret_cast<const f32x4*>(sb + q * 16);
            acc0[q * 4 + 0] = sv[0];
            acc0[q * 4 + 1] = sv[1];
            acc0[q * 4 + 2] = sv[2];
            acc0[q * 4 + 3] = sv[3];
        }
        f32x16 acc1 = acc0;

        const char* abase = smem + cur + ln * 512;
        const int swz = (ln & 7);
#pragma unroll
        for (int kg = 0; kg < 16; ++kg) {
            bf16x8 af = *reinterpret_cast<const bf16x8*>(
                abase + ((((kg << 1) + h) ^ swz) << 4));
            acc0 = __builtin_amdgcn_mfma_f32_32x32x16_bf16(af, brow0[kg], acc0, 0, 0, 0);
            acc1 = __builtin_amdgcn_mfma_f32_32x32x16_bf16(af, brow1[kg], acc1, 0, 0, 0);
        }

        const unsigned int cb0 = (unsigned int)(colbase + (t << 5) + (h << 2));
#pragma unroll
        for (int r = 0; r < 16; ++r) {
            unsigned int cidx = cb0 + (r & 3) + ((r >> 2) << 3);
            push6(bk0, ((unsigned int)acc0[r] << 12) | cidx);
            push6(bk1, ((unsigned int)acc1[r] << 12) | cidx);
        }
        __syncthreads();
    }

    size_t p0 = ((size_t)b << 12) + myrow0;
    unsigned int* op0 = cand + p0 * 48 + stripe * 12 + h * 6;
    unsigned int* op1 = cand + (p0 + 32) * 48 + stripe * 12 + h * 6;
#pragma unroll
    for (int s = 0; s < 6; ++s) { op0[s] = bk0[s]; op1[s] = bk1[s]; }
}

// ---------------- k1s: key-top-16 of 48; resolve boundary or flag ----------------
__global__ __launch_bounds__(256) void sel_kernel(const unsigned int* __restrict__ cand,
                                                  unsigned short* __restrict__ c16,
                                                  int* __restrict__ idxout,
                                                  unsigned char* __restrict__ flag) {
    int p = blockIdx.x * 256 + threadIdx.x;
    const unsigned int* cp = cand + (size_t)p * 48;
    unsigned int tk[16];
#pragma unroll
    for (int s = 0; s < 16; ++s) tk[s] = 0xFFFFFFFFu;
    for (int j = 0; j < 48; ++j) {
        unsigned int key = cp[j];
#pragma unroll
        for (int s = 15; s > 0; --s) tk[s] = med3u(tk[s - 1], tk[s], key);
        tk[0] = min(tk[0], key);
    }
    unsigned short* op = c16 + (size_t)p * 16;
#pragma unroll
    for (int s = 0; s < 16; ++s) op[s] = (unsigned short)(tk[s] & 4095u);
    int* ip = idxout + (size_t)p * K_;
#pragma unroll
    for (int s = 0; s < 6; ++s) ip[s] = (int)(tk[s] & 4095u);
    float d6 = (float)(tk[5] >> 12) * 0.001953125f;
    float d7 = (float)(tk[6] >> 12) * 0.001953125f;
    flag[p] = (d7 - d6 < 0.4f) ? 1 : 0;
}

// ------- k1b: fp64 exact re-rank of 16 candidates (flagged points only) -------
__global__ __launch_bounds__(256) void refine_kernel(const float* __restrict__ x,
                                                     const unsigned short* __restrict__ c16,
                                                     const unsigned char* __restrict__ flag,
                                                     int* __restrict__ idxout) {
    int wv = threadIdx.x >> 6;
    int lane = threadIdx.x & 63;
    const int bid = blockIdx.x;
    const int nbk = ((bid & 7) << 10) | (bid >> 3);
    int p = nbk * 4 + wv;
    if (!flag[p]) return;
    int b = p >> 12;
    int vi = p & 4095;
    const float* Xb = x + ((size_t)b << 12) * E_;
    const int half = lane >> 5;
    const int hl = lane & 31;

    double xi[8];
#pragma unroll
    for (int t = 0; t < 8; ++t) xi[t] = (double)Xb[(size_t)vi * E_ + hl + t * 32];

    double bdist[6]; int bidx[6];
#pragma unroll
    for (int s = 0; s < 6; ++s) { bdist[s] = DBL_MAX; bidx[s] = 0x7fffffff; }

    const unsigned short* cp = c16 + (size_t)p * 16;
    for (int c = 0; c < 16; c += 2) {
        int jme = cp[c + half];
        const float* Xj = Xb + (size_t)jme * E_;
        double s = 0.0;
#pragma unroll
        for (int t = 0; t < 8; ++t) {
            double d = xi[t] - (double)Xj[hl + t * 32];
            s = fma(d, d, s);
        }
#pragma unroll
        for (int off = 16; off; off >>= 1) s += __shfl_xor(s, off);
        double sv[2];
        sv[0] = __shfl(s, 0);
        sv[1] = __shfl(s, 32);
        int jv[2] = { (int)cp[c], (int)cp[c + 1] };
#pragma unroll
        for (int q = 0; q < 2; ++q) {
            double sq_ = sv[q]; int j = jv[q];
            if (sq_ < bdist[5] || (sq_ == bdist[5] && j < bidx[5])) {
                bdist[5] = sq_; bidx[5] = j;
#pragma unroll
                for (int t = 5; t > 0; --t) {
                    if (bdist[t] < bdist[t - 1] ||
                        (bdist[t] == bdist[t - 1] && bidx[t] < bidx[t - 1])) {
                        double td = bdist[t]; bdist[t] = bdist[t - 1]; bdist[t - 1] = td;
                        int    ti = bidx[t];  bidx[t]  = bidx[t - 1];  bidx[t - 1]  = ti;
                    } else break;
                }
            }
        }
    }
    if (lane == 0) {
        int* op = idxout + (size_t)p * K_;
#pragma unroll
        for (int s = 0; s < 6; ++s) op[s] = bidx[s];
    }
}

// -------- k2: QKV projection, 128 rows/block dual-acc, W prefetched 1 ct ahead --------
// R19 lesson: unpipelined W loads serialize (load->MFMA chains, VALUBusy 2.7%).
// Explicit wf/wn register double-buffer gives load->use distance of 16 MFMAs.
__global__ __launch_bounds__(256, 2) void proj_mfma(const unsigned short* __restrict__ xh,
                                                    const unsigned short* __restrict__ Wh,
                                                    unsigned short* __restrict__ Y) {
    const int tid = threadIdx.x;
    const int w = tid >> 6, l = tid & 63, cl = l & 15, g = l >> 4;
    const int row0 = blockIdx.x * 128;
    const int wsel = blockIdx.y;                    // 0=Q,1=K,2=V
    const unsigned short* W = Wh + (size_t)wsel * 65536;

    bf16x8 a0[8], a1[8];
    const int ar0 = row0 + (w << 4) + cl;
#pragma unroll
    for (int ks = 0; ks < 8; ++ks) {
        a0[ks] = *reinterpret_cast<const bf16x8*>(xh + ((size_t)ar0 << 8) + ks * 32 + g * 8);
        a1[ks] = *reinterpret_cast<const bf16x8*>(xh + ((size_t)(ar0 + 64) << 8) + ks * 32 + g * 8);
    }

    // prefetch ct=0 W fragments
    bf16x8 wf[8];
    {
        const unsigned short* Wr = W + (size_t)cl * 256 + g * 8;
#pragma unroll
        for (int ks = 0; ks < 8; ++ks)
            wf[ks] = *reinterpret_cast<const bf16x8*>(Wr + ks * 32);
    }

#pragma unroll
    for (int ct = 0; ct < 16; ++ct) {
        bf16x8 wn[8];
        if (ct < 15) {
            const unsigned short* Wr = W + (size_t)((ct + 1) * 16 + cl) * 256 + g * 8;
#pragma unroll
            for (int ks = 0; ks < 8; ++ks)
                wn[ks] = *reinterpret_cast<const bf16x8*>(Wr + ks * 32);
        }
        f32x4 acc0 = {0.f, 0.f, 0.f, 0.f};
        f32x4 acc1 = {0.f, 0.f, 0.f, 0.f};
#pragma unroll
        for (int ks = 0; ks < 8; ++ks) {
            acc0 = __builtin_amdgcn_mfma_f32_16x16x32_bf16(a0[ks], wf[ks], acc0, 0, 0, 0);
            acc1 = __builtin_amdgcn_mfma_f32_16x16x32_bf16(a1[ks], wf[ks], acc1, 0, 0, 0);
        }
#pragma unroll
        for (int r = 0; r < 4; ++r) {
            size_t row = row0 + (w << 4) + (g << 2) + r;
            Y[row * 768 + wsel * 256 + ct * 16 + cl] = f2bf(acc0[r]);
            Y[(row + 64) * 768 + wsel * 256 + ct * 16 + cl] = f2bf(acc1[r]);
        }
#pragma unroll
        for (int ks = 0; ks < 8; ++ks) wf[ks] = wn[ks];
    }
}

// ---- k3: fused attention + Wo GEMM + residual. Block = 16 points ----
__global__ __launch_bounds__(256) void attn16_kernel(const unsigned short* __restrict__ Y,
                                                     const int* __restrict__ idx,
                                                     const unsigned short* __restrict__ WoH,
                                                     const float* __restrict__ x,
                                                     float* __restrict__ out,
                                                     float* __restrict__ xw) {
    __shared__ __align__(16) unsigned short P[16][264];   // +8 pad vs bank conflicts
    const int bid = blockIdx.x;                           // 2048
    const int blk = ((bid & 7) << 8) | (bid >> 3);        // XCD swizzle: XCD c -> batch c
    const int w = threadIdx.x >> 6;
    const int l = threadIdx.x & 63;
    const int p0 = blk * 16;
    const int b = p0 >> 12;
    const size_t bbase = (size_t)(b << 12) * 768;

    for (int j = 0; j < 4; ++j) {
        const int p = p0 + w * 4 + j;
        const int* ip = idx + (size_t)p * K_;
        int nb[K_];
#pragma unroll
        for (int k = 0; k < K_; ++k) nb[k] = ip[k];

        const unsigned short* Yp = Y + (size_t)p * 768;
        ushort4 q4 = *reinterpret_cast<const ushort4*>(Yp + l * 4);
        ushort4 s4 = *reinterpret_cast<const ushort4*>(Yp + 512 + l * 4);
        float q0 = bf2f(q4.x), q1 = bf2f(q4.y), q2 = bf2f(q4.z), q3 = bf2f(q4.w);
        float v0 = bf2f(s4.x), v1 = bf2f(s4.y), v2 = bf2f(s4.z), v3 = bf2f(s4.w);

        float sc[K_];
#pragma unroll
        for (int k = 0; k < K_; ++k) {
            ushort4 k4 = *reinterpret_cast<const ushort4*>(
                Y + bbase + (size_t)nb[k] * 768 + 256 + l * 4);
            float s = q0 * bf2f(k4.x) + q1 * bf2f(k4.y)
                    + q2 * bf2f(k4.z) + q3 * bf2f(k4.w);
            s += __shfl_xor(s, 1);
            s += __shfl_xor(s, 2);
            s += __shfl_xor(s, 4);
            sc[k] = s * 0.17677669529663687f;   // 1/sqrt(32)
        }
        float m = sc[0];
#pragma unroll
        for (int k = 1; k < K_; ++k) m = fmaxf(m, sc[k]);
        float e[K_], sum = 0.f;
#pragma unroll
        for (int k = 0; k < K_; ++k) { e[k] = __expf(sc[k] - m); sum += e[k]; }
        float inv = 1.f / sum;

        float o0 = 0.f, o1 = 0.f, o2 = 0.f, o3 = 0.f;
        float hs[K_];
#pragma unroll
        for (int k = 0; k < K_; ++k) {
            float a = e[k] * inv;
            ushort4 z4 = *reinterpret_cast<const ushort4*>(
                Y + bbase + (size_t)nb[k] * 768 + 512 + l * 4);
            o0 += a * (bf2f(z4.x) - v0);
            o1 += a * (bf2f(z4.y) - v1);
            o2 += a * (bf2f(z4.z) - v2);
            o3 += a * (bf2f(z4.w) - v3);
            float t = a;
            t += __shfl_xor(t, 8);
            t += __shfl_xor(t, 16);
            t += __shfl_xor(t, 32);
            hs[k] = t * 0.125f;
        }
        ushort o4[4] = { f2bf(o0), f2bf(o1), f2bf(o2), f2bf(o3) };
        *reinterpret_cast<ushort4*>(&P[w * 4 + j][l * 4]) =
            *reinterpret_cast<ushort4*>(o4);
        if (l < K_) atomicAdd(&xw[(b << 12) + nb[l]], hs[l]);
    }
    __syncthreads();

    // 16x256 P @ Wo^T + x ; wave w computes output cols [w*64, w*64+64)
    const int cl = l & 15, g = l >> 4;
    bf16x8 a[8];
#pragma unroll
    for (int ks = 0; ks < 8; ++ks)
        a[ks] = *reinterpret_cast<const bf16x8*>(&P[cl][ks * 32 + g * 8]);

#pragma unroll
    for (int ct = 0; ct < 4; ++ct) {
        const int col0 = w * 64 + ct * 16;
        f32x4 acc = {0.f, 0.f, 0.f, 0.f};
        const unsigned short* Wr = WoH + (size_t)(col0 + cl) * 256 + g * 8;
#pragma unroll
        for (int ks = 0; ks < 8; ++ks) {
            bf16x8 bf = *reinterpret_cast<const bf16x8*>(Wr + ks * 32);
            acc = __builtin_amdgcn_mfma_f32_16x16x32_bf16(a[ks], bf, acc, 0, 0, 0);
        }
#pragma unroll
        for (int r = 0; r < 4; ++r) {
            size_t o = (size_t)(p0 + (g << 2) + r) * E_ + col0 + cl;
            out[o] = acc[r] + x[o];
        }
    }
}

extern "C" void kernel_launch(void* const* d_in, const int* in_sizes, int n_in,
                              void* d_out, int out_size, void* d_ws, size_t ws_size,
                              hipStream_t stream) {
    const float* x  = (const float*)d_in[0];
    const float* Wq = (const float*)d_in[1];
    const float* Wk = (const float*)d_in[2];
    const float* Wv = (const float*)d_in[3];
    const float* Wo = (const float*)d_in[4];

    float* out = (float*)d_out;
    float* xw  = out + (size_t)NPTS * E_;   // second output [B,V]

    // workspace layout (R15-proven)
    char* ws = (char*)d_ws;
    float*          sqpw  = (float*)(ws + 131072);               // 128 KiB (permuted)
    unsigned int*   candw = (unsigned int*)(ws + 262144);        // 6 MiB (48 uint/pt)
    int*            idxw  = (int*)(ws + 6553600);                // 768 KiB
    unsigned char*  flagw = (unsigned char*)(ws + 7340032);      // 32 KiB
    unsigned short* Wh    = (unsigned short*)(ws + 7372800);     // 512 KiB (4 matrices)
    unsigned short* c16w  = (unsigned short*)(ws + 7897088);     // 1 MiB
    unsigned short* Xh    = (unsigned short*)(ws + 8945664);     // 16 MiB
    unsigned short* Y     = (unsigned short*)(ws + 25722880);    // 48 MiB bf16 [32768][768]

    cvtsq_kernel<<<4096 + 128, 256, 0, stream>>>(x, Wq, Wk, Wv, Wo, Xh, Wh, sqpw, xw);
    knn13_kernel<<<dim3(V_ / 256, 4, B_), 256, 0, stream>>>(Xh, sqpw, candw);
    sel_kernel<<<NPTS / 256, 256, 0, stream>>>(candw, c16w, idxw, flagw);
    refine_kernel<<<NPTS / 4, 256, 0, stream>>>(x, c16w, flagw, idxw);
    proj_mfma<<<dim3(NPTS / 128, 3), 256, 0, stream>>>(Xh, Wh, Y);
    attn16_kernel<<<NPTS / 16, 256, 0, stream>>>(Y, idxw, Wh + 3 * 65536, x, out, xw);
}

// Round 21
// 195.267 us; speedup vs baseline: 1.3810x; 1.1741x over previous
//
#include <hip/hip_runtime.h>
#include <cfloat>
#include <math.h>

#define B_   8
#define V_   4096
#define E_   256
#define K_   6
#define H_   8
#define HD_  32
#define NPTS (B_*V_)

typedef __bf16 bf16x8 __attribute__((ext_vector_type(8)));
typedef float  f32x4  __attribute__((ext_vector_type(4)));
typedef float  f32x16 __attribute__((ext_vector_type(16)));

__device__ __forceinline__ float bf2f(unsigned short u) {
    return __uint_as_float(((unsigned int)u) << 16);
}
__device__ __forceinline__ unsigned short f2bf(float f) {
    unsigned int u = __float_as_uint(f);
    return (unsigned short)((u + 0x7fffu + ((u >> 16) & 1u)) >> 16);
}
__device__ __forceinline__ unsigned int med3u(unsigned int a, unsigned int b,
                                              unsigned int c) {
    unsigned int d;
    asm("v_med3_u32 %0, %1, %2, %3" : "=v"(d) : "v"(a), "v"(b), "v"(c));
    return d;
}
// branchless sorted-top-6 insert (single definition -> no transcription bugs)
__device__ __forceinline__ void push6(unsigned int (&k6)[6], unsigned int key) {
    k6[5] = med3u(k6[4], k6[5], key);
    k6[4] = med3u(k6[3], k6[4], key);
    k6[3] = med3u(k6[2], k6[3], key);
    k6[2] = med3u(k6[1], k6[2], key);
    k6[1] = med3u(k6[0], k6[1], key);
    k6[0] = min(k6[0], key);
}
// bf16 bitwise *(-1024): exponent+10, sign flip (exact; no denorm/overflow for our data)
__device__ __forceinline__ unsigned int bfscale2(unsigned int u) {
    return (u + 0x05000500u) ^ 0x80008000u;
}

// ------ k0: fp32->bf16 of x + W matrices; sq -> permuted (sq+600)*512; xw zeroing ------
__global__ __launch_bounds__(256) void cvtsq_kernel(const float* __restrict__ x,
                                                    const float* __restrict__ Wq,
                                                    const float* __restrict__ Wk,
                                                    const float* __restrict__ Wv,
                                                    const float* __restrict__ Wo,
                                                    unsigned short* __restrict__ xh,
                                                    unsigned short* __restrict__ Wh,
                                                    float* __restrict__ sqp,
                                                    float* __restrict__ xw) {
    const int bx = blockIdx.x;
    if (bx < 4096) {
        size_t i = ((size_t)bx * 256 + threadIdx.x) * 8;
        float4 a = *reinterpret_cast<const float4*>(x + i);
        float4 b = *reinterpret_cast<const float4*>(x + i + 4);
        ushort o[8] = { f2bf(a.x), f2bf(a.y), f2bf(a.z), f2bf(a.w),
                        f2bf(b.x), f2bf(b.y), f2bf(b.z), f2bf(b.w) };
        *reinterpret_cast<uint4*>(xh + i) = *reinterpret_cast<uint4*>(o);
        float s = a.x*a.x + a.y*a.y + a.z*a.z + a.w*a.w
                + b.x*b.x + b.y*b.y + b.z*b.z + b.w*b.w;
        s += __shfl_xor(s, 1);
        s += __shfl_xor(s, 2);
        s += __shfl_xor(s, 4);
        s += __shfl_xor(s, 8);
        s += __shfl_xor(s, 16);
        if ((threadIdx.x & 31) == 0) {
            int p = bx * 8 + (threadIdx.x >> 5);
            int b_ = p >> 12, col = p & 4095;
            int stripe = col >> 10, cc = col & 1023;
            int t = cc >> 5, rem = cc & 31;
            int h = (rem >> 2) & 1;
            int reg = (rem & 3) | ((rem >> 3) << 2);
            int i2 = (b_ << 12) | (stripe << 10) | (t << 5) | (h << 4) | reg;
            sqp[i2] = (s + 600.f) * 512.f;
        }
    } else {
        const int wb = bx - 4096;               // 0..127
        xw[wb * 256 + threadIdx.x] = 0.f;       // 128x256 = 32768 -> full xw zeroing
        const int m = wb >> 5;
        const float* src = (m == 0) ? Wq : (m == 1) ? Wk : (m == 2) ? Wv : Wo;
        unsigned short* dst = Wh + (size_t)m * 65536;
        size_t i = ((size_t)(wb & 31) * 256 + threadIdx.x) * 8;
        float4 a = *reinterpret_cast<const float4*>(src + i);
        float4 b = *reinterpret_cast<const float4*>(src + i + 4);
        ushort o[8] = { f2bf(a.x), f2bf(a.y), f2bf(a.z), f2bf(a.w),
                        f2bf(b.x), f2bf(b.y), f2bf(b.z), f2bf(b.w) };
        *reinterpret_cast<uint4*>(dst + i) = *reinterpret_cast<uint4*>(o);
    }
}

// ---- k1: 32x32x16 MFMA Gram, 64 rows/wave (dual B-set), 4 stripes of 1024 ----
__global__ __launch_bounds__(256, 2) void knn13_kernel(const unsigned short* __restrict__ xh,
                                                       const float* __restrict__ sqp,
                                                       unsigned int* __restrict__ cand) {
    __shared__ __align__(16) char smem[36864];   // 2x16KB tiles + 4KB sqp stripe

    const int b      = blockIdx.z;
    const int row0   = blockIdx.x * 256;
    const int stripe = blockIdx.y;
    const int colbase = stripe * 1024;
    const int tid = threadIdx.x;
    const int w   = tid >> 6;
    const int l   = tid & 63;
    const int ln  = l & 31;
    const int h   = l >> 5;
    const unsigned short* Xb = xh + ((size_t)b << 12) * E_;

    const int myrow0 = row0 + (w << 6) + ln;
    bf16x8 brow0[16], brow1[16];
#pragma unroll
    for (int kg = 0; kg < 16; ++kg) {
        uint4 u0 = *reinterpret_cast<const uint4*>(
            Xb + ((size_t)myrow0 << 8) + kg * 16 + h * 8);
        uint4 u1 = *reinterpret_cast<const uint4*>(
            Xb + ((size_t)(myrow0 + 32) << 8) + kg * 16 + h * 8);
        u0.x = bfscale2(u0.x); u0.y = bfscale2(u0.y);
        u0.z = bfscale2(u0.z); u0.w = bfscale2(u0.w);
        u1.x = bfscale2(u1.x); u1.y = bfscale2(u1.y);
        u1.z = bfscale2(u1.z); u1.w = bfscale2(u1.w);
        brow0[kg] = *reinterpret_cast<bf16x8*>(&u0);
        brow1[kg] = *reinterpret_cast<bf16x8*>(&u1);
    }

    unsigned int bk0[6], bk1[6];
#pragma unroll
    for (int s = 0; s < 6; ++s) { bk0[s] = 0xFFFFFFFFu; bk1[s] = 0xFFFFFFFFu; }

    __builtin_amdgcn_global_load_lds(
        (const __attribute__((address_space(1))) void*)
            (sqp + ((size_t)(b * 4 + stripe) << 10) + tid * 4),
        (__attribute__((address_space(3))) void*)(smem + 32768 + tid * 16), 16, 0, 0);
#pragma unroll
    for (int it = 0; it < 4; ++it) {
        int li = it * 256 + tid, col = li >> 5, sl = li & 31;
        const unsigned short* gp =
            Xb + ((size_t)(colbase + col) << 8) + ((sl ^ (col & 7)) << 3);
        __builtin_amdgcn_global_load_lds(
            (const __attribute__((address_space(1))) void*)gp,
            (__attribute__((address_space(3))) void*)(smem + li * 16), 16, 0, 0);
    }
    __syncthreads();

    for (int t = 0; t < 32; ++t) {
        const int cur = (t & 1) * 16384;
        if (t < 31) {
            char* nbuf = smem + (cur ^ 16384);
            const int c0n = colbase + (t + 1) * 32;
#pragma unroll
            for (int it = 0; it < 4; ++it) {
                int li = it * 256 + tid, col = li >> 5, sl = li & 31;
                const unsigned short* gp =
                    Xb + ((size_t)(c0n + col) << 8) + ((sl ^ (col & 7)) << 3);
                __builtin_amdgcn_global_load_lds(
                    (const __attribute__((address_space(1))) void*)gp,
                    (__attribute__((address_space(3))) void*)(nbuf + li * 16), 16, 0, 0);
            }
        }
        const char* sb = smem + 32768 + t * 128 + h * 64;
        f32x16 acc0;
#pragma unroll
        for (int q = 0; q < 4; ++q) {
            f32x4 sv = *reinterpret_cast<const f32x4*>(sb + q * 16);
            acc0[q * 4 + 0] = sv[0];
            acc0[q * 4 + 1] = sv[1];
            acc0[q * 4 + 2] = sv[2];
            acc0[q * 4 + 3] = sv[3];
        }
        f32x16 acc1 = acc0;

        const char* abase = smem + cur + ln * 512;
        const int swz = (ln & 7);
#pragma unroll
        for (int kg = 0; kg < 16; ++kg) {
            bf16x8 af = *reinterpret_cast<const bf16x8*>(
                abase + ((((kg << 1) + h) ^ swz) << 4));
            acc0 = __builtin_amdgcn_mfma_f32_32x32x16_bf16(af, brow0[kg], acc0, 0, 0, 0);
            acc1 = __builtin_amdgcn_mfma_f32_32x32x16_bf16(af, brow1[kg], acc1, 0, 0, 0);
        }

        const unsigned int cb0 = (unsigned int)(colbase + (t << 5) + (h << 2));
#pragma unroll
        for (int r = 0; r < 16; ++r) {
            unsigned int cidx = cb0 + (r & 3) + ((r >> 2) << 3);
            push6(bk0, ((unsigned int)acc0[r] << 12) | cidx);
            push6(bk1, ((unsigned int)acc1[r] << 12) | cidx);
        }
        __syncthreads();
    }

    size_t p0 = ((size_t)b << 12) + myrow0;
    unsigned int* op0 = cand + p0 * 48 + stripe * 12 + h * 6;
    unsigned int* op1 = cand + (p0 + 32) * 48 + stripe * 12 + h * 6;
#pragma unroll
    for (int s = 0; s < 6; ++s) { op0[s] = bk0[s]; op1[s] = bk1[s]; }
}

// ---------------- k1s: key-top-16 of 48; resolve boundary or flag ----------------
__global__ __launch_bounds__(256) void sel_kernel(const unsigned int* __restrict__ cand,
                                                  unsigned short* __restrict__ c16,
                                                  int* __restrict__ idxout,
                                                  unsigned char* __restrict__ flag) {
    int p = blockIdx.x * 256 + threadIdx.x;
    const unsigned int* cp = cand + (size_t)p * 48;
    unsigned int tk[16];
#pragma unroll
    for (int s = 0; s < 16; ++s) tk[s] = 0xFFFFFFFFu;
    for (int j = 0; j < 48; ++j) {
        unsigned int key = cp[j];
#pragma unroll
        for (int s = 15; s > 0; --s) tk[s] = med3u(tk[s - 1], tk[s], key);
        tk[0] = min(tk[0], key);
    }
    unsigned short* op = c16 + (size_t)p * 16;
#pragma unroll
    for (int s = 0; s < 16; ++s) op[s] = (unsigned short)(tk[s] & 4095u);
    int* ip = idxout + (size_t)p * K_;
#pragma unroll
    for (int s = 0; s < 6; ++s) ip[s] = (int)(tk[s] & 4095u);
    float d6 = (float)(tk[5] >> 12) * 0.001953125f;
    float d7 = (float)(tk[6] >> 12) * 0.001953125f;
    flag[p] = (d7 - d6 < 0.4f) ? 1 : 0;
}

// ------- k1b: fp64 exact re-rank of 16 candidates (flagged points only) -------
__global__ __launch_bounds__(256) void refine_kernel(const float* __restrict__ x,
                                                     const unsigned short* __restrict__ c16,
                                                     const unsigned char* __restrict__ flag,
                                                     int* __restrict__ idxout) {
    int wv = threadIdx.x >> 6;
    int lane = threadIdx.x & 63;
    const int bid = blockIdx.x;
    const int nbk = ((bid & 7) << 10) | (bid >> 3);
    int p = nbk * 4 + wv;
    if (!flag[p]) return;
    int b = p >> 12;
    int vi = p & 4095;
    const float* Xb = x + ((size_t)b << 12) * E_;
    const int half = lane >> 5;
    const int hl = lane & 31;

    double xi[8];
#pragma unroll
    for (int t = 0; t < 8; ++t) xi[t] = (double)Xb[(size_t)vi * E_ + hl + t * 32];

    double bdist[6]; int bidx[6];
#pragma unroll
    for (int s = 0; s < 6; ++s) { bdist[s] = DBL_MAX; bidx[s] = 0x7fffffff; }

    const unsigned short* cp = c16 + (size_t)p * 16;
    for (int c = 0; c < 16; c += 2) {
        int jme = cp[c + half];
        const float* Xj = Xb + (size_t)jme * E_;
        double s = 0.0;
#pragma unroll
        for (int t = 0; t < 8; ++t) {
            double d = xi[t] - (double)Xj[hl + t * 32];
            s = fma(d, d, s);
        }
#pragma unroll
        for (int off = 16; off; off >>= 1) s += __shfl_xor(s, off);
        double sv[2];
        sv[0] = __shfl(s, 0);
        sv[1] = __shfl(s, 32);
        int jv[2] = { (int)cp[c], (int)cp[c + 1] };
#pragma unroll
        for (int q = 0; q < 2; ++q) {
            double sq_ = sv[q]; int j = jv[q];
            if (sq_ < bdist[5] || (sq_ == bdist[5] && j < bidx[5])) {
                bdist[5] = sq_; bidx[5] = j;
#pragma unroll
                for (int t = 5; t > 0; --t) {
                    if (bdist[t] < bdist[t - 1] ||
                        (bdist[t] == bdist[t - 1] && bidx[t] < bidx[t - 1])) {
                        double td = bdist[t]; bdist[t] = bdist[t - 1]; bdist[t - 1] = td;
                        int    ti = bidx[t];  bidx[t]  = bidx[t - 1];  bidx[t - 1]  = ti;
                    } else break;
                }
            }
        }
    }
    if (lane == 0) {
        int* op = idxout + (size_t)p * K_;
#pragma unroll
        for (int s = 0; s < 6; ++s) op[s] = bidx[s];
    }
}

// -------- k2: QKV projection; W staged through LDS (knn-style double buffer) --------
// R20 lesson: per-wave W streaming from L2 is latency-serialized (MfmaUtil<5%).
// global_load_lds DMA + barrier pipeline stages each 2-ct W tile ONCE per block.
__global__ __launch_bounds__(256, 2) void proj_mfma(const unsigned short* __restrict__ xh,
                                                    const unsigned short* __restrict__ Wh,
                                                    unsigned short* __restrict__ Y) {
    __shared__ __align__(16) char smem[32768];   // 2 x 16KB W ct-pair tiles
    const int tid = threadIdx.x;
    const int w = tid >> 6, l = tid & 63, cl = l & 15, g = l >> 4;
    const int row0 = blockIdx.x * 128;
    const int wsel = blockIdx.y;                    // 0=Q,1=K,2=V
    const unsigned short* W = Wh + (size_t)wsel * 65536;

    bf16x8 a0[8], a1[8];
    const int ar0 = row0 + (w << 4) + cl;
#pragma unroll
    for (int ks = 0; ks < 8; ++ks) {
        a0[ks] = *reinterpret_cast<const bf16x8*>(xh + ((size_t)ar0 << 8) + ks * 32 + g * 8);
        a1[ks] = *reinterpret_cast<const bf16x8*>(xh + ((size_t)(ar0 + 64) << 8) + ks * 32 + g * 8);
    }

    // stage ct-pair 0 (32 W-rows x 256 k, source-side XOR swizzle, linear dest)
#pragma unroll
    for (int it = 0; it < 4; ++it) {
        int li = it * 256 + tid, col = li >> 5, sl = li & 31;
        const unsigned short* gp = W + ((size_t)col << 8) + ((sl ^ (col & 7)) << 3);
        __builtin_amdgcn_global_load_lds(
            (const __attribute__((address_space(1))) void*)gp,
            (__attribute__((address_space(3))) void*)(smem + li * 16), 16, 0, 0);
    }
    __syncthreads();

    for (int tp = 0; tp < 8; ++tp) {
        const int cur = (tp & 1) * 16384;
        if (tp < 7) {
            char* nbuf = smem + (cur ^ 16384);
            const int colb = (tp + 1) * 32;
#pragma unroll
            for (int it = 0; it < 4; ++it) {
                int li = it * 256 + tid, col = li >> 5, sl = li & 31;
                const unsigned short* gp =
                    W + ((size_t)(colb + col) << 8) + ((sl ^ (col & 7)) << 3);
                __builtin_amdgcn_global_load_lds(
                    (const __attribute__((address_space(1))) void*)gp,
                    (__attribute__((address_space(3))) void*)(nbuf + li * 16), 16, 0, 0);
            }
        }
#pragma unroll
        for (int c01 = 0; c01 < 2; ++c01) {
            const int ct = tp * 2 + c01;
            const int wr = c01 * 16 + cl;           // W-row within 32-row tile
            const char* wbase = smem + cur + wr * 512;
            const int swz = wr & 7;
            f32x4 acc0 = {0.f, 0.f, 0.f, 0.f};
            f32x4 acc1 = {0.f, 0.f, 0.f, 0.f};
#pragma unroll
            for (int ks = 0; ks < 8; ++ks) {
                bf16x8 wf = *reinterpret_cast<const bf16x8*>(
                    wbase + ((((ks << 2) + g) ^ swz) << 4));
                acc0 = __builtin_amdgcn_mfma_f32_16x16x32_bf16(a0[ks], wf, acc0, 0, 0, 0);
                acc1 = __builtin_amdgcn_mfma_f32_16x16x32_bf16(a1[ks], wf, acc1, 0, 0, 0);
            }
#pragma unroll
            for (int r = 0; r < 4; ++r) {
                size_t row = row0 + (w << 4) + (g << 2) + r;
                Y[row * 768 + wsel * 256 + ct * 16 + cl] = f2bf(acc0[r]);
                Y[(row + 64) * 768 + wsel * 256 + ct * 16 + cl] = f2bf(acc1[r]);
            }
        }
        __syncthreads();   // prefetch landed + all reads of cur done
    }
}

// ---- k3: fused attention + Wo GEMM + residual. Block = 16 points ----
__global__ __launch_bounds__(256) void attn16_kernel(const unsigned short* __restrict__ Y,
                                                     const int* __restrict__ idx,
                                                     const unsigned short* __restrict__ WoH,
                                                     const float* __restrict__ x,
                                                     float* __restrict__ out,
                                                     float* __restrict__ xw) {
    __shared__ __align__(16) unsigned short P[16][264];   // +8 pad vs bank conflicts
    const int bid = blockIdx.x;                           // 2048
    const int blk = ((bid & 7) << 8) | (bid >> 3);        // XCD swizzle: XCD c -> batch c
    const int w = threadIdx.x >> 6;
    const int l = threadIdx.x & 63;
    const int p0 = blk * 16;
    const int b = p0 >> 12;
    const size_t bbase = (size_t)(b << 12) * 768;

    for (int j = 0; j < 4; ++j) {
        const int p = p0 + w * 4 + j;
        const int* ip = idx + (size_t)p * K_;
        int nb[K_];
#pragma unroll
        for (int k = 0; k < K_; ++k) nb[k] = ip[k];

        const unsigned short* Yp = Y + (size_t)p * 768;
        ushort4 q4 = *reinterpret_cast<const ushort4*>(Yp + l * 4);
        ushort4 s4 = *reinterpret_cast<const ushort4*>(Yp + 512 + l * 4);
        float q0 = bf2f(q4.x), q1 = bf2f(q4.y), q2 = bf2f(q4.z), q3 = bf2f(q4.w);
        float v0 = bf2f(s4.x), v1 = bf2f(s4.y), v2 = bf2f(s4.z), v3 = bf2f(s4.w);

        float sc[K_];
#pragma unroll
        for (int k = 0; k < K_; ++k) {
            ushort4 k4 = *reinterpret_cast<const ushort4*>(
                Y + bbase + (size_t)nb[k] * 768 + 256 + l * 4);
            float s = q0 * bf2f(k4.x) + q1 * bf2f(k4.y)
                    + q2 * bf2f(k4.z) + q3 * bf2f(k4.w);
            s += __shfl_xor(s, 1);
            s += __shfl_xor(s, 2);
            s += __shfl_xor(s, 4);
            sc[k] = s * 0.17677669529663687f;   // 1/sqrt(32)
        }
        float m = sc[0];
#pragma unroll
        for (int k = 1; k < K_; ++k) m = fmaxf(m, sc[k]);
        float e[K_], sum = 0.f;
#pragma unroll
        for (int k = 0; k < K_; ++k) { e[k] = __expf(sc[k] - m); sum += e[k]; }
        float inv = 1.f / sum;

        float o0 = 0.f, o1 = 0.f, o2 = 0.f, o3 = 0.f;
        float hs[K_];
#pragma unroll
        for (int k = 0; k < K_; ++k) {
            float a = e[k] * inv;
            ushort4 z4 = *reinterpret_cast<const ushort4*>(
                Y + bbase + (size_t)nb[k] * 768 + 512 + l * 4);
            o0 += a * (bf2f(z4.x) - v0);
            o1 += a * (bf2f(z4.y) - v1);
            o2 += a * (bf2f(z4.z) - v2);
            o3 += a * (bf2f(z4.w) - v3);
            float t = a;
            t += __shfl_xor(t, 8);
            t += __shfl_xor(t, 16);
            t += __shfl_xor(t, 32);
            hs[k] = t * 0.125f;
        }
        ushort o4[4] = { f2bf(o0), f2bf(o1), f2bf(o2), f2bf(o3) };
        *reinterpret_cast<ushort4*>(&P[w * 4 + j][l * 4]) =
            *reinterpret_cast<ushort4*>(o4);
        if (l < K_) atomicAdd(&xw[(b << 12) + nb[l]], hs[l]);
    }
    __syncthreads();

    // 16x256 P @ Wo^T + x ; wave w computes output cols [w*64, w*64+64)
    const int cl = l & 15, g = l >> 4;
    bf16x8 a[8];
#pragma unroll
    for (int ks = 0; ks < 8; ++ks)
        a[ks] = *reinterpret_cast<const bf16x8*>(&P[cl][ks * 32 + g * 8]);

#pragma unroll
    for (int ct = 0; ct < 4; ++ct) {
        const int col0 = w * 64 + ct * 16;
        f32x4 acc = {0.f, 0.f, 0.f, 0.f};
        const unsigned short* Wr = WoH + (size_t)(col0 + cl) * 256 + g * 8;
#pragma unroll
        for (int ks = 0; ks < 8; ++ks) {
            bf16x8 bf = *reinterpret_cast<const bf16x8*>(Wr + ks * 32);
            acc = __builtin_amdgcn_mfma_f32_16x16x32_bf16(a[ks], bf, acc, 0, 0, 0);
        }
#pragma unroll
        for (int r = 0; r < 4; ++r) {
            size_t o = (size_t)(p0 + (g << 2) + r) * E_ + col0 + cl;
            out[o] = acc[r] + x[o];
        }
    }
}

extern "C" void kernel_launch(void* const* d_in, const int* in_sizes, int n_in,
                              void* d_out, int out_size, void* d_ws, size_t ws_size,
                              hipStream_t stream) {
    const float* x  = (const float*)d_in[0];
    const float* Wq = (const float*)d_in[1];
    const float* Wk = (const float*)d_in[2];
    const float* Wv = (const float*)d_in[3];
    const float* Wo = (const float*)d_in[4];

    float* out = (float*)d_out;
    float* xw  = out + (size_t)NPTS * E_;   // second output [B,V]

    // workspace layout (R15-proven)
    char* ws = (char*)d_ws;
    float*          sqpw  = (float*)(ws + 131072);               // 128 KiB (permuted)
    unsigned int*   candw = (unsigned int*)(ws + 262144);        // 6 MiB (48 uint/pt)
    int*            idxw  = (int*)(ws + 6553600);                // 768 KiB
    unsigned char*  flagw = (unsigned char*)(ws + 7340032);      // 32 KiB
    unsigned short* Wh    = (unsigned short*)(ws + 7372800);     // 512 KiB (4 matrices)
    unsigned short* c16w  = (unsigned short*)(ws + 7897088);     // 1 MiB
    unsigned short* Xh    = (unsigned short*)(ws + 8945664);     // 16 MiB
    unsigned short* Y     = (unsigned short*)(ws + 25722880);    // 48 MiB bf16 [32768][768]

    cvtsq_kernel<<<4096 + 128, 256, 0, stream>>>(x, Wq, Wk, Wv, Wo, Xh, Wh, sqpw, xw);
    knn13_kernel<<<dim3(V_ / 256, 4, B_), 256, 0, stream>>>(Xh, sqpw, candw);
    sel_kernel<<<NPTS / 256, 256, 0, stream>>>(candw, c16w, idxw, flagw);
    refine_kernel<<<NPTS / 4, 256, 0, stream>>>(x, c16w, flagw, idxw);
    proj_mfma<<<dim3(NPTS / 128, 3), 256, 0, stream>>>(Xh, Wh, Y);
    attn16_kernel<<<NPTS / 16, 256, 0, stream>>>(Y, idxw, Wh + 3 * 65536, x, out, xw);
}

// Round 22
// 183.739 us; speedup vs baseline: 1.4677x; 1.0627x over previous
//
#include <hip/hip_runtime.h>
#include <cfloat>
#include <math.h>

#define B_   8
#define V_   4096
#define E_   256
#define K_   6
#define H_   8
#define HD_  32
#define NPTS (B_*V_)

typedef __bf16 bf16x8 __attribute__((ext_vector_type(8)));
typedef float  f32x4  __attribute__((ext_vector_type(4)));
typedef float  f32x16 __attribute__((ext_vector_type(16)));

__device__ __forceinline__ float bf2f(unsigned short u) {
    return __uint_as_float(((unsigned int)u) << 16);
}
__device__ __forceinline__ unsigned short f2bf(float f) {
    unsigned int u = __float_as_uint(f);
    return (unsigned short)((u + 0x7fffu + ((u >> 16) & 1u)) >> 16);
}
__device__ __forceinline__ unsigned int med3u(unsigned int a, unsigned int b,
                                              unsigned int c) {
    unsigned int d;
    asm("v_med3_u32 %0, %1, %2, %3" : "=v"(d) : "v"(a), "v"(b), "v"(c));
    return d;
}
// branchless sorted-top-6 insert (single definition -> no transcription bugs)
__device__ __forceinline__ void push6(unsigned int (&k6)[6], unsigned int key) {
    k6[5] = med3u(k6[4], k6[5], key);
    k6[4] = med3u(k6[3], k6[4], key);
    k6[3] = med3u(k6[2], k6[3], key);
    k6[2] = med3u(k6[1], k6[2], key);
    k6[1] = med3u(k6[0], k6[1], key);
    k6[0] = min(k6[0], key);
}
// bf16 bitwise *(-1024): exponent+10, sign flip (exact; no denorm/overflow for our data)
__device__ __forceinline__ unsigned int bfscale2(unsigned int u) {
    return (u + 0x05000500u) ^ 0x80008000u;
}

// ------ k0: fp32->bf16 of x + W matrices; sq -> permuted (sq+600)*512; xw zeroing ------
__global__ __launch_bounds__(256) void cvtsq_kernel(const float* __restrict__ x,
                                                    const float* __restrict__ Wq,
                                                    const float* __restrict__ Wk,
                                                    const float* __restrict__ Wv,
                                                    const float* __restrict__ Wo,
                                                    unsigned short* __restrict__ xh,
                                                    unsigned short* __restrict__ Wh,
                                                    float* __restrict__ sqp,
                                                    float* __restrict__ xw) {
    const int bx = blockIdx.x;
    if (bx < 4096) {
        size_t i = ((size_t)bx * 256 + threadIdx.x) * 8;
        float4 a = *reinterpret_cast<const float4*>(x + i);
        float4 b = *reinterpret_cast<const float4*>(x + i + 4);
        ushort o[8] = { f2bf(a.x), f2bf(a.y), f2bf(a.z), f2bf(a.w),
                        f2bf(b.x), f2bf(b.y), f2bf(b.z), f2bf(b.w) };
        *reinterpret_cast<uint4*>(xh + i) = *reinterpret_cast<uint4*>(o);
        float s = a.x*a.x + a.y*a.y + a.z*a.z + a.w*a.w
                + b.x*b.x + b.y*b.y + b.z*b.z + b.w*b.w;
        s += __shfl_xor(s, 1);
        s += __shfl_xor(s, 2);
        s += __shfl_xor(s, 4);
        s += __shfl_xor(s, 8);
        s += __shfl_xor(s, 16);
        if ((threadIdx.x & 31) == 0) {
            int p = bx * 8 + (threadIdx.x >> 5);
            int b_ = p >> 12, col = p & 4095;
            int stripe = col >> 10, cc = col & 1023;
            int t = cc >> 5, rem = cc & 31;
            int h = (rem >> 2) & 1;
            int reg = (rem & 3) | ((rem >> 3) << 2);
            int i2 = (b_ << 12) | (stripe << 10) | (t << 5) | (h << 4) | reg;
            sqp[i2] = (s + 600.f) * 512.f;
        }
    } else {
        const int wb = bx - 4096;               // 0..127
        xw[wb * 256 + threadIdx.x] = 0.f;       // 128x256 = 32768 -> full xw zeroing
        const int m = wb >> 5;
        const float* src = (m == 0) ? Wq : (m == 1) ? Wk : (m == 2) ? Wv : Wo;
        unsigned short* dst = Wh + (size_t)m * 65536;
        size_t i = ((size_t)(wb & 31) * 256 + threadIdx.x) * 8;
        float4 a = *reinterpret_cast<const float4*>(src + i);
        float4 b = *reinterpret_cast<const float4*>(src + i + 4);
        ushort o[8] = { f2bf(a.x), f2bf(a.y), f2bf(a.z), f2bf(a.w),
                        f2bf(b.x), f2bf(b.y), f2bf(b.z), f2bf(b.w) };
        *reinterpret_cast<uint4*>(dst + i) = *reinterpret_cast<uint4*>(o);
    }
}

// ---- k1: 32x32x16 MFMA Gram, 64 rows/wave (dual B-set), 4 stripes of 1024 ----
__global__ __launch_bounds__(256, 2) void knn13_kernel(const unsigned short* __restrict__ xh,
                                                       const float* __restrict__ sqp,
                                                       unsigned int* __restrict__ cand) {
    __shared__ __align__(16) char smem[36864];   // 2x16KB tiles + 4KB sqp stripe

    const int b      = blockIdx.z;
    const int row0   = blockIdx.x * 256;
    const int stripe = blockIdx.y;
    const int colbase = stripe * 1024;
    const int tid = threadIdx.x;
    const int w   = tid >> 6;
    const int l   = tid & 63;
    const int ln  = l & 31;
    const int h   = l >> 5;
    const unsigned short* Xb = xh + ((size_t)b << 12) * E_;

    const int myrow0 = row0 + (w << 6) + ln;
    bf16x8 brow0[16], brow1[16];
#pragma unroll
    for (int kg = 0; kg < 16; ++kg) {
        uint4 u0 = *reinterpret_cast<const uint4*>(
            Xb + ((size_t)myrow0 << 8) + kg * 16 + h * 8);
        uint4 u1 = *reinterpret_cast<const uint4*>(
            Xb + ((size_t)(myrow0 + 32) << 8) + kg * 16 + h * 8);
        u0.x = bfscale2(u0.x); u0.y = bfscale2(u0.y);
        u0.z = bfscale2(u0.z); u0.w = bfscale2(u0.w);
        u1.x = bfscale2(u1.x); u1.y = bfscale2(u1.y);
        u1.z = bfscale2(u1.z); u1.w = bfscale2(u1.w);
        brow0[kg] = *reinterpret_cast<bf16x8*>(&u0);
        brow1[kg] = *reinterpret_cast<bf16x8*>(&u1);
    }

    unsigned int bk0[6], bk1[6];
#pragma unroll
    for (int s = 0; s < 6; ++s) { bk0[s] = 0xFFFFFFFFu; bk1[s] = 0xFFFFFFFFu; }

    __builtin_amdgcn_global_load_lds(
        (const __attribute__((address_space(1))) void*)
            (sqp + ((size_t)(b * 4 + stripe) << 10) + tid * 4),
        (__attribute__((address_space(3))) void*)(smem + 32768 + tid * 16), 16, 0, 0);
#pragma unroll
    for (int it = 0; it < 4; ++it) {
        int li = it * 256 + tid, col = li >> 5, sl = li & 31;
        const unsigned short* gp =
            Xb + ((size_t)(colbase + col) << 8) + ((sl ^ (col & 7)) << 3);
        __builtin_amdgcn_global_load_lds(
            (const __attribute__((address_space(1))) void*)gp,
            (__attribute__((address_space(3))) void*)(smem + li * 16), 16, 0, 0);
    }
    __syncthreads();

    for (int t = 0; t < 32; ++t) {
        const int cur = (t & 1) * 16384;
        if (t < 31) {
            char* nbuf = smem + (cur ^ 16384);
            const int c0n = colbase + (t + 1) * 32;
#pragma unroll
            for (int it = 0; it < 4; ++it) {
                int li = it * 256 + tid, col = li >> 5, sl = li & 31;
                const unsigned short* gp =
                    Xb + ((size_t)(c0n + col) << 8) + ((sl ^ (col & 7)) << 3);
                __builtin_amdgcn_global_load_lds(
                    (const __attribute__((address_space(1))) void*)gp,
                    (__attribute__((address_space(3))) void*)(nbuf + li * 16), 16, 0, 0);
            }
        }
        const char* sb = smem + 32768 + t * 128 + h * 64;
        f32x16 acc0;
#pragma unroll
        for (int q = 0; q < 4; ++q) {
            f32x4 sv = *reinterpret_cast<const f32x4*>(sb + q * 16);
            acc0[q * 4 + 0] = sv[0];
            acc0[q * 4 + 1] = sv[1];
            acc0[q * 4 + 2] = sv[2];
            acc0[q * 4 + 3] = sv[3];
        }
        f32x16 acc1 = acc0;

        const char* abase = smem + cur + ln * 512;
        const int swz = (ln & 7);
#pragma unroll
        for (int kg = 0; kg < 16; ++kg) {
            bf16x8 af = *reinterpret_cast<const bf16x8*>(
                abase + ((((kg << 1) + h) ^ swz) << 4));
            acc0 = __builtin_amdgcn_mfma_f32_32x32x16_bf16(af, brow0[kg], acc0, 0, 0, 0);
            acc1 = __builtin_amdgcn_mfma_f32_32x32x16_bf16(af, brow1[kg], acc1, 0, 0, 0);
        }

        const unsigned int cb0 = (unsigned int)(colbase + (t << 5) + (h << 2));
#pragma unroll
        for (int r = 0; r < 16; ++r) {
            unsigned int cidx = cb0 + (r & 3) + ((r >> 2) << 3);
            push6(bk0, ((unsigned int)acc0[r] << 12) | cidx);
            push6(bk1, ((unsigned int)acc1[r] << 12) | cidx);
        }
        __syncthreads();
    }

    size_t p0 = ((size_t)b << 12) + myrow0;
    unsigned int* op0 = cand + p0 * 48 + stripe * 12 + h * 6;
    unsigned int* op1 = cand + (p0 + 32) * 48 + stripe * 12 + h * 6;
#pragma unroll
    for (int s = 0; s < 6; ++s) { op0[s] = bk0[s]; op1[s] = bk1[s]; }
}

// ---------------- k1s: key-top-16 of 48; resolve boundary or flag ----------------
__global__ __launch_bounds__(256) void sel_kernel(const unsigned int* __restrict__ cand,
                                                  unsigned short* __restrict__ c16,
                                                  int* __restrict__ idxout,
                                                  unsigned char* __restrict__ flag) {
    int p = blockIdx.x * 256 + threadIdx.x;
    const unsigned int* cp = cand + (size_t)p * 48;
    unsigned int tk[16];
#pragma unroll
    for (int s = 0; s < 16; ++s) tk[s] = 0xFFFFFFFFu;
    for (int j = 0; j < 48; ++j) {
        unsigned int key = cp[j];
#pragma unroll
        for (int s = 15; s > 0; --s) tk[s] = med3u(tk[s - 1], tk[s], key);
        tk[0] = min(tk[0], key);
    }
    unsigned short* op = c16 + (size_t)p * 16;
#pragma unroll
    for (int s = 0; s < 16; ++s) op[s] = (unsigned short)(tk[s] & 4095u);
    int* ip = idxout + (size_t)p * K_;
#pragma unroll
    for (int s = 0; s < 6; ++s) ip[s] = (int)(tk[s] & 4095u);
    float d6 = (float)(tk[5] >> 12) * 0.001953125f;
    float d7 = (float)(tk[6] >> 12) * 0.001953125f;
    flag[p] = (d7 - d6 < 0.4f) ? 1 : 0;
}

// ------- k1b: fp64 exact re-rank of 16 candidates (flagged points only) -------
__global__ __launch_bounds__(256) void refine_kernel(const float* __restrict__ x,
                                                     const unsigned short* __restrict__ c16,
                                                     const unsigned char* __restrict__ flag,
                                                     int* __restrict__ idxout) {
    int wv = threadIdx.x >> 6;
    int lane = threadIdx.x & 63;
    const int bid = blockIdx.x;
    const int nbk = ((bid & 7) << 10) | (bid >> 3);
    int p = nbk * 4 + wv;
    if (!flag[p]) return;
    int b = p >> 12;
    int vi = p & 4095;
    const float* Xb = x + ((size_t)b << 12) * E_;
    const int half = lane >> 5;
    const int hl = lane & 31;

    double xi[8];
#pragma unroll
    for (int t = 0; t < 8; ++t) xi[t] = (double)Xb[(size_t)vi * E_ + hl + t * 32];

    double bdist[6]; int bidx[6];
#pragma unroll
    for (int s = 0; s < 6; ++s) { bdist[s] = DBL_MAX; bidx[s] = 0x7fffffff; }

    const unsigned short* cp = c16 + (size_t)p * 16;
    for (int c = 0; c < 16; c += 2) {
        int jme = cp[c + half];
        const float* Xj = Xb + (size_t)jme * E_;
        double s = 0.0;
#pragma unroll
        for (int t = 0; t < 8; ++t) {
            double d = xi[t] - (double)Xj[hl + t * 32];
            s = fma(d, d, s);
        }
#pragma unroll
        for (int off = 16; off; off >>= 1) s += __shfl_xor(s, off);
        double sv[2];
        sv[0] = __shfl(s, 0);
        sv[1] = __shfl(s, 32);
        int jv[2] = { (int)cp[c], (int)cp[c + 1] };
#pragma unroll
        for (int q = 0; q < 2; ++q) {
            double sq_ = sv[q]; int j = jv[q];
            if (sq_ < bdist[5] || (sq_ == bdist[5] && j < bidx[5])) {
                bdist[5] = sq_; bidx[5] = j;
#pragma unroll
                for (int t = 5; t > 0; --t) {
                    if (bdist[t] < bdist[t - 1] ||
                        (bdist[t] == bdist[t - 1] && bidx[t] < bidx[t - 1])) {
                        double td = bdist[t]; bdist[t] = bdist[t - 1]; bdist[t - 1] = td;
                        int    ti = bidx[t];  bidx[t]  = bidx[t - 1];  bidx[t - 1]  = ti;
                    } else break;
                }
            }
        }
    }
    if (lane == 0) {
        int* op = idxout + (size_t)p * K_;
#pragma unroll
        for (int s = 0; s < 6; ++s) op[s] = bidx[s];
    }
}

// -------- k2: QKV projection; W staged through LDS (knn-style double buffer) --------
__global__ __launch_bounds__(256, 2) void proj_mfma(const unsigned short* __restrict__ xh,
                                                    const unsigned short* __restrict__ Wh,
                                                    unsigned short* __restrict__ Y) {
    __shared__ __align__(16) char smem[32768];   // 2 x 16KB W ct-pair tiles
    const int tid = threadIdx.x;
    const int w = tid >> 6, l = tid & 63, cl = l & 15, g = l >> 4;
    const int row0 = blockIdx.x * 128;
    const int wsel = blockIdx.y;                    // 0=Q,1=K,2=V
    const unsigned short* W = Wh + (size_t)wsel * 65536;

    bf16x8 a0[8], a1[8];
    const int ar0 = row0 + (w << 4) + cl;
#pragma unroll
    for (int ks = 0; ks < 8; ++ks) {
        a0[ks] = *reinterpret_cast<const bf16x8*>(xh + ((size_t)ar0 << 8) + ks * 32 + g * 8);
        a1[ks] = *reinterpret_cast<const bf16x8*>(xh + ((size_t)(ar0 + 64) << 8) + ks * 32 + g * 8);
    }

#pragma unroll
    for (int it = 0; it < 4; ++it) {
        int li = it * 256 + tid, col = li >> 5, sl = li & 31;
        const unsigned short* gp = W + ((size_t)col << 8) + ((sl ^ (col & 7)) << 3);
        __builtin_amdgcn_global_load_lds(
            (const __attribute__((address_space(1))) void*)gp,
            (__attribute__((address_space(3))) void*)(smem + li * 16), 16, 0, 0);
    }
    __syncthreads();

    for (int tp = 0; tp < 8; ++tp) {
        const int cur = (tp & 1) * 16384;
        if (tp < 7) {
            char* nbuf = smem + (cur ^ 16384);
            const int colb = (tp + 1) * 32;
#pragma unroll
            for (int it = 0; it < 4; ++it) {
                int li = it * 256 + tid, col = li >> 5, sl = li & 31;
                const unsigned short* gp =
                    W + ((size_t)(colb + col) << 8) + ((sl ^ (col & 7)) << 3);
                __builtin_amdgcn_global_load_lds(
                    (const __attribute__((address_space(1))) void*)gp,
                    (__attribute__((address_space(3))) void*)(nbuf + li * 16), 16, 0, 0);
            }
        }
#pragma unroll
        for (int c01 = 0; c01 < 2; ++c01) {
            const int ct = tp * 2 + c01;
            const int wr = c01 * 16 + cl;           // W-row within 32-row tile
            const char* wbase = smem + cur + wr * 512;
            const int swz = wr & 7;
            f32x4 acc0 = {0.f, 0.f, 0.f, 0.f};
            f32x4 acc1 = {0.f, 0.f, 0.f, 0.f};
#pragma unroll
            for (int ks = 0; ks < 8; ++ks) {
                bf16x8 wf = *reinterpret_cast<const bf16x8*>(
                    wbase + ((((ks << 2) + g) ^ swz) << 4));
                acc0 = __builtin_amdgcn_mfma_f32_16x16x32_bf16(a0[ks], wf, acc0, 0, 0, 0);
                acc1 = __builtin_amdgcn_mfma_f32_16x16x32_bf16(a1[ks], wf, acc1, 0, 0, 0);
            }
#pragma unroll
            for (int r = 0; r < 4; ++r) {
                size_t row = row0 + (w << 4) + (g << 2) + r;
                Y[row * 768 + wsel * 256 + ct * 16 + cl] = f2bf(acc0[r]);
                Y[(row + 64) * 768 + wsel * 256 + ct * 16 + cl] = f2bf(acc1[r]);
            }
        }
        __syncthreads();   // prefetch landed + all reads of cur done
    }
}

// ---- k3: fused attention + Wo-staged GEMM + residual. Block = 32 points:
// 4 waves x 8 points sequential gather; P -> LDS; Wo staged via global_load_lds
// double buffer (R19/R21 lesson: per-wave W streams latency-serialize). ----
__global__ __launch_bounds__(256) void attn32_kernel(const unsigned short* __restrict__ Y,
                                                     const int* __restrict__ idx,
                                                     const unsigned short* __restrict__ WoH,
                                                     const float* __restrict__ x,
                                                     float* __restrict__ out,
                                                     float* __restrict__ xw) {
    __shared__ __align__(16) unsigned short P[32][264];   // 16.9KB, +8 pad
    __shared__ __align__(16) char wsmem[32768];           // 2 x 16KB Wo tiles
    const int bid = blockIdx.x;                           // 1024
    const int blk = ((bid & 7) << 7) | (bid >> 3);        // XCD swizzle: batch = bid&7
    const int tid = threadIdx.x;
    const int w = tid >> 6;
    const int l = tid & 63;
    const int p0 = blk * 32;
    const int b = p0 >> 12;
    const size_t bbase = (size_t)(b << 12) * 768;

    for (int j = 0; j < 8; ++j) {
        const int pr = w * 8 + j;
        const int p = p0 + pr;
        const int* ip = idx + (size_t)p * K_;
        int nb[K_];
#pragma unroll
        for (int k = 0; k < K_; ++k) nb[k] = ip[k];

        const unsigned short* Yp = Y + (size_t)p * 768;
        ushort4 q4 = *reinterpret_cast<const ushort4*>(Yp + l * 4);
        ushort4 s4 = *reinterpret_cast<const ushort4*>(Yp + 512 + l * 4);
        float q0 = bf2f(q4.x), q1 = bf2f(q4.y), q2 = bf2f(q4.z), q3 = bf2f(q4.w);
        float v0 = bf2f(s4.x), v1 = bf2f(s4.y), v2 = bf2f(s4.z), v3 = bf2f(s4.w);

        float sc[K_];
#pragma unroll
        for (int k = 0; k < K_; ++k) {
            ushort4 k4 = *reinterpret_cast<const ushort4*>(
                Y + bbase + (size_t)nb[k] * 768 + 256 + l * 4);
            float s = q0 * bf2f(k4.x) + q1 * bf2f(k4.y)
                    + q2 * bf2f(k4.z) + q3 * bf2f(k4.w);
            s += __shfl_xor(s, 1);
            s += __shfl_xor(s, 2);
            s += __shfl_xor(s, 4);
            sc[k] = s * 0.17677669529663687f;   // 1/sqrt(32)
        }
        float m = sc[0];
#pragma unroll
        for (int k = 1; k < K_; ++k) m = fmaxf(m, sc[k]);
        float e[K_], sum = 0.f;
#pragma unroll
        for (int k = 0; k < K_; ++k) { e[k] = __expf(sc[k] - m); sum += e[k]; }
        float inv = 1.f / sum;

        float o0 = 0.f, o1 = 0.f, o2 = 0.f, o3 = 0.f;
        float hs[K_];
#pragma unroll
        for (int k = 0; k < K_; ++k) {
            float a = e[k] * inv;
            ushort4 z4 = *reinterpret_cast<const ushort4*>(
                Y + bbase + (size_t)nb[k] * 768 + 512 + l * 4);
            o0 += a * (bf2f(z4.x) - v0);
            o1 += a * (bf2f(z4.y) - v1);
            o2 += a * (bf2f(z4.z) - v2);
            o3 += a * (bf2f(z4.w) - v3);
            float t = a;
            t += __shfl_xor(t, 8);
            t += __shfl_xor(t, 16);
            t += __shfl_xor(t, 32);
            hs[k] = t * 0.125f;
        }
        ushort o4[4] = { f2bf(o0), f2bf(o1), f2bf(o2), f2bf(o3) };
        *reinterpret_cast<ushort4*>(&P[pr][l * 4]) = *reinterpret_cast<ushort4*>(o4);
        if (l < K_) atomicAdd(&xw[(b << 12) + nb[l]], hs[l]);
    }
    __syncthreads();

    // GEMM: 32x256 P @ Wo^T + x. Tile tp = 32 Wo rows = cts {2tp, 2tp+1}.
    // Wave w -> P-row half (w&1), ct = 2tp + (w>>1): 4 waves cover 2x2 tiles.
    const int cl = l & 15, g = l >> 4;
    const int p16 = (w & 1) << 4;
    const int cth = w >> 1;
    bf16x8 a[8];
#pragma unroll
    for (int ks = 0; ks < 8; ++ks)
        a[ks] = *reinterpret_cast<const bf16x8*>(&P[p16 + cl][ks * 32 + g * 8]);

    // stage Wo tile 0 (rows 0..31, source-side XOR swizzle, linear dest)
#pragma unroll
    for (int it = 0; it < 4; ++it) {
        int li = it * 256 + tid, row = li >> 5, sl = li & 31;
        const unsigned short* gp = WoH + ((size_t)row << 8) + ((sl ^ (row & 7)) << 3);
        __builtin_amdgcn_global_load_lds(
            (const __attribute__((address_space(1))) void*)gp,
            (__attribute__((address_space(3))) void*)(wsmem + li * 16), 16, 0, 0);
    }
    __syncthreads();

    for (int tp = 0; tp < 8; ++tp) {
        const int cur = (tp & 1) * 16384;
        if (tp < 7) {
            char* nbuf = wsmem + (cur ^ 16384);
            const int rowb = (tp + 1) * 32;
#pragma unroll
            for (int it = 0; it < 4; ++it) {
                int li = it * 256 + tid, row = li >> 5, sl = li & 31;
                const unsigned short* gp =
                    WoH + ((size_t)(rowb + row) << 8) + ((sl ^ (row & 7)) << 3);
                __builtin_amdgcn_global_load_lds(
                    (const __attribute__((address_space(1))) void*)gp,
                    (__attribute__((address_space(3))) void*)(nbuf + li * 16), 16, 0, 0);
            }
        }
        const int ct = tp * 2 + cth;
        const int wr = cth * 16 + cl;           // Wo row within 32-row tile
        const char* wbase = wsmem + cur + wr * 512;
        const int swz = wr & 7;
        f32x4 acc = {0.f, 0.f, 0.f, 0.f};
#pragma unroll
        for (int ks = 0; ks < 8; ++ks) {
            bf16x8 wf = *reinterpret_cast<const bf16x8*>(
                wbase + ((((ks << 2) + g) ^ swz) << 4));
            acc = __builtin_amdgcn_mfma_f32_16x16x32_bf16(a[ks], wf, acc, 0, 0, 0);
        }
#pragma unroll
        for (int r = 0; r < 4; ++r) {
            size_t o = (size_t)(p0 + p16 + (g << 2) + r) * E_ + ct * 16 + cl;
            out[o] = acc[r] + x[o];
        }
        __syncthreads();   // prefetch landed + all reads of cur done
    }
}

extern "C" void kernel_launch(void* const* d_in, const int* in_sizes, int n_in,
                              void* d_out, int out_size, void* d_ws, size_t ws_size,
                              hipStream_t stream) {
    const float* x  = (const float*)d_in[0];
    const float* Wq = (const float*)d_in[1];
    const float* Wk = (const float*)d_in[2];
    const float* Wv = (const float*)d_in[3];
    const float* Wo = (const float*)d_in[4];

    float* out = (float*)d_out;
    float* xw  = out + (size_t)NPTS * E_;   // second output [B,V]

    // workspace layout (R15-proven)
    char* ws = (char*)d_ws;
    float*          sqpw  = (float*)(ws + 131072);               // 128 KiB (permuted)
    unsigned int*   candw = (unsigned int*)(ws + 262144);        // 6 MiB (48 uint/pt)
    int*            idxw  = (int*)(ws + 6553600);                // 768 KiB
    unsigned char*  flagw = (unsigned char*)(ws + 7340032);      // 32 KiB
    unsigned short* Wh    = (unsigned short*)(ws + 7372800);     // 512 KiB (4 matrices)
    unsigned short* c16w  = (unsigned short*)(ws + 7897088);     // 1 MiB
    unsigned short* Xh    = (unsigned short*)(ws + 8945664);     // 16 MiB
    unsigned short* Y     = (unsigned short*)(ws + 25722880);    // 48 MiB bf16 [32768][768]

    cvtsq_kernel<<<4096 + 128, 256, 0, stream>>>(x, Wq, Wk, Wv, Wo, Xh, Wh, sqpw, xw);
    knn13_kernel<<<dim3(V_ / 256, 4, B_), 256, 0, stream>>>(Xh, sqpw, candw);
    sel_kernel<<<NPTS / 256, 256, 0, stream>>>(candw, c16w, idxw, flagw);
    refine_kernel<<<NPTS / 4, 256, 0, stream>>>(x, c16w, flagw, idxw);
    proj_mfma<<<dim3(NPTS / 128, 3), 256, 0, stream>>>(Xh, Wh, Y);
    attn32_kernel<<<NPTS / 32, 256, 0, stream>>>(Y, idxw, Wh + 3 * 65536, x, out, xw);
}